// Round 2
// baseline (29037.619 us; speedup 1.0000x reference)
//
#include <hip/hip_runtime.h>

#define B_N 256
#define F_N 256
#define NJ3 51
#define DH 512
#define G4 2048
#define CTX 563
#define CTXSTR (F_N * CTX)            // 144128
#define OUT0 (B_N * F_N * NJ3)        // 3342336
#define CTXOFF OUT0
#define NBLK 256
#define NTHR 512
#define LDSZ (65536 + 65536 + 64 * 33 * 4)   // B0h/fold + B1 + gsm = 139520

typedef __attribute__((ext_vector_type(8))) short short8;
typedef __attribute__((ext_vector_type(4))) float floatx4;

__device__ __forceinline__ short f2bf(float f) {
  unsigned u = __float_as_uint(f);
  u = (u + 0x7fffu + ((u >> 16) & 1u)) >> 16;
  return (short)u;
}

#define MFMA(a, b, c) __builtin_amdgcn_mfma_f32_16x16x32_bf16((a), (b), (c), 0, 0, 0)

// ---------------------------------------------------------------------------
// Generic fp32 tiled GEMM (pre/post passes).
// mode 0: relu -> out_f[M,N]
// mode 1: x_emb -> bf16 MFMA-A-frag layout [t=f][rowtile][kc][lane][8], row=b, k=n
// mode 2: z3 scatter: n<512 -> h0 frag, <1024 -> h1 frag, <1536 -> c0 f32, else c1
// mode 3: preds dual-write: out_f[m*51+n] and out_f2[m*563+512+n]
// ---------------------------------------------------------------------------
__global__ __launch_bounds__(256) void gemm_f32(
    const float* __restrict__ A, int lda,
    const float* __restrict__ Bw, const float* __restrict__ bias,
    int M, int N, int K, int mode,
    float* __restrict__ out_f, float* __restrict__ out_f2,
    short* __restrict__ out_h0, short* __restrict__ out_h1,
    float* __restrict__ out_c0, float* __restrict__ out_c1)
{
  __shared__ float As[16][64];
  __shared__ float Bs[16][68];
  int tid = threadIdx.x;
  int n0 = blockIdx.x * 64, m0 = blockIdx.y * 64;
  float acc[4][4] = {{0.f}};
  int ar = tid >> 2, ak = (tid & 3) * 4;
  int bk = tid >> 6, bn = tid & 63;
  int tm = (tid >> 4) * 4, tn = (tid & 15) * 4;
  for (int k0 = 0; k0 < K; k0 += 16) {
#pragma unroll
    for (int i = 0; i < 4; i++) {
      int kk = ak + i;
      float v = 0.f;
      if (k0 + kk < K) v = A[(long)(m0 + ar) * lda + k0 + kk];
      As[kk][ar] = v;
    }
#pragma unroll
    for (int i = 0; i < 4; i++) {
      int kk = bk + i * 4;
      float v = 0.f;
      if (k0 + kk < K && n0 + bn < N) v = Bw[(long)(k0 + kk) * N + n0 + bn];
      Bs[kk][bn] = v;
    }
    __syncthreads();
#pragma unroll
    for (int kk = 0; kk < 16; kk++) {
      float a0[4], b0[4];
#pragma unroll
      for (int i = 0; i < 4; i++) a0[i] = As[kk][tm + i];
#pragma unroll
      for (int j = 0; j < 4; j++) b0[j] = Bs[kk][tn + j];
#pragma unroll
      for (int i = 0; i < 4; i++)
#pragma unroll
        for (int j = 0; j < 4; j++) acc[i][j] += a0[i] * b0[j];
    }
    __syncthreads();
  }
#pragma unroll
  for (int i = 0; i < 4; i++) {
    int m = m0 + tm + i;
#pragma unroll
    for (int j = 0; j < 4; j++) {
      int n = n0 + tn + j;
      if (n >= N) continue;
      float v = acc[i][j] + bias[n];
      if (mode == 0) {
        out_f[(long)m * N + n] = fmaxf(v, 0.f);
      } else if (mode == 1) {
        int b = m >> 8, f = m & 255;
        long idx = ((((long)f * 16 + (b >> 4)) * 16 + (n >> 5)) * 64 +
                    ((n >> 3) & 3) * 16 + (b & 15)) * 8 + (n & 7);
        out_h0[idx] = f2bf(v);
      } else if (mode == 2) {
        int d = n & 511;
        long fi = (((long)(m >> 4) * 16 + (d >> 5)) * 64 +
                   ((d >> 3) & 3) * 16 + (m & 15)) * 8 + (d & 7);
        if (n < 512)       out_h0[fi] = f2bf(v);
        else if (n < 1024) out_h1[fi] = f2bf(v);
        else if (n < 1536) out_c0[m * 512 + d] = v;
        else               out_c1[m * 512 + d] = v;
      } else {
        out_f[(long)m * NJ3 + n] = v;
        out_f2[(long)m * CTX + 512 + n] = v;
      }
    }
  }
}

// ---------------------------------------------------------------------------
// Pack weights (fp32 -> bf16) into MFMA B-fragment layout (same as round 0):
// dst[((ntg*KC + kc)*64 + lane)*8 + j] = B[kc*32+(lane>>4)*8+j][ntg*16+(lane&15)]
// col j' = 4*d + gate  ->  original gate row jo = gate*512 + d
// mode 0: B0A (t=0): [Wih0_x(512) | Whh0(512) | Wih0_pred pad64]  KC=34
// mode 1: B0B (t>0): [Wih0_x(512) | Whh0(512) | dec_W@Wp^T(512)]  KC=48
// mode 2: B1:        [Wih1(512)   | Whh1(512)]                     KC=32
// ---------------------------------------------------------------------------
__global__ __launch_bounds__(256) void pack_b(
    short* __restrict__ dst, int KC, int mode,
    const float* __restrict__ Wih0, const float* __restrict__ Whh0,
    const float* __restrict__ Wih1, const float* __restrict__ Whh1,
    const float* __restrict__ dec_W)
{
  int idx = blockIdx.x * 256 + threadIdx.x;
  int total = KC * 32 * G4;
  if (idx >= total) return;
  int j = idx & 7;
  int l = (idx >> 3) & 63;
  int tt = idx >> 9;
  int kc = tt % KC;
  int nt = tt / KC;
  int k = kc * 32 + ((l >> 4) << 3) + j;
  int jp = nt * 16 + (l & 15);
  int jo = ((jp & 3) << 9) + (jp >> 2);
  float v = 0.f;
  if (mode == 0) {
    if (k < 512) v = Wih0[jo * 563 + k];
    else if (k < 1024) v = Whh0[jo * 512 + k - 512];
    else { int p = k - 1024; v = (p < NJ3) ? Wih0[jo * 563 + 512 + p] : 0.f; }
  } else if (mode == 1) {
    if (k < 512) v = Wih0[jo * 563 + k];
    else if (k < 1024) v = Whh0[jo * 512 + k - 512];
    else {
      int dd = k - 1024;
      float s = 0.f;
      for (int p = 0; p < NJ3; p++) s += dec_W[dd * NJ3 + p] * Wih0[jo * 563 + 512 + p];
      v = s;
    }
  } else {
    if (k < 512) v = Wih1[jo * 512 + k];
    else v = Whh1[jo * 512 + k - 512];
  }
  dst[idx] = f2bf(v);
}

// biases in j'=4d+g order; bias0B includes dec_b fold; pred0pad bf16 [256][64];
// zero flag counters.
__global__ __launch_bounds__(256) void prep_small(
    float* __restrict__ bias0A, float* __restrict__ bias0B, float* __restrict__ bias1,
    short* __restrict__ pred0pad, int* __restrict__ flags,
    const float* __restrict__ bih0, const float* __restrict__ bhh0,
    const float* __restrict__ bih1, const float* __restrict__ bhh1,
    const float* __restrict__ Wih0, const float* __restrict__ dec_b,
    const float* __restrict__ init_p)
{
  int i = blockIdx.x * 256 + threadIdx.x;
  if (i < G4) {
    int jo = ((i & 3) << 9) + (i >> 2);
    float b0 = bih0[jo] + bhh0[jo];
    bias0A[i] = b0;
    float s = 0.f;
    for (int p = 0; p < NJ3; p++) s += dec_b[p] * Wih0[jo * 563 + 512 + p];
    bias0B[i] = b0 + s;
    bias1[i] = bih1[jo] + bhh1[jo];
  }
  if (i < 16384) {
    int b = i >> 6, p = i & 63;
    pred0pad[i] = (p < NJ3) ? f2bf(init_p[b * 85 + p]) : (short)0;
  }
  if (i < 512) flags[i] = 0;
}

// ---------------------------------------------------------------------------
// Persistent cooperative scan. 256 blocks x 512 threads, 1 block/CU.
// block: cg = bid&63 (gate-col group: 32 j'-cols = 8 d), rg = bid>>6 (64 rows).
// LDS: B0 hh+fold frags (64KB) + B1 frags (64KB) + gate tile gsm (8.4KB).
// Dataflow sync: h0done[t]/h1done[t] counters, release/acquire, agent scope.
// c-state in registers for the whole scan. h bufs double-buffered in A-frag
// layout. x-embed K-segment computed before any wait (dependency-free).
// ---------------------------------------------------------------------------
__global__ __launch_bounds__(512) void scan_persist(
    const short8* __restrict__ xembF, const short8* __restrict__ B0Ag,
    const short8* __restrict__ B0Bg, const short8* __restrict__ B1g,
    short* __restrict__ h0b0, short* __restrict__ h0b1,
    short* __restrict__ h1b0, short* __restrict__ h1b1,
    const float* __restrict__ c0init, const float* __restrict__ c1init,
    const float* __restrict__ bias0A, const float* __restrict__ bias0B,
    const float* __restrict__ bias1, const short* __restrict__ pred0,
    float* __restrict__ ctxo, int* __restrict__ h0done, int* __restrict__ h1done)
{
  extern __shared__ char smem[];
  short8* ldsB0 = (short8*)smem;             // [nt2][kc32][lane64]
  short8* ldsB1 = (short8*)(smem + 65536);   // [nt2][kc32][lane64]
  float*  gsm   = (float*)(smem + 131072);   // [64][33]

  const int tid  = threadIdx.x;
  const int lane = tid & 63, wave = tid >> 6;
  const int cg = blockIdx.x & 63, rg = blockIdx.x >> 6;
  const int nt = wave >> 2, mt = wave & 3;
  const int rt = rg * 4 + mt;                 // global A rowtile (0..15)

  // stage both weight slices into LDS (one-time)
  for (int i = tid; i < 4096; i += NTHR) {
    int nt_ = i >> 11, kc_ = (i >> 6) & 31, l_ = i & 63;
    ldsB0[i] = B0Bg[(((cg * 2 + nt_) * 48) + 16 + kc_) * 64 + l_];
    ldsB1[i] = B1g[(((cg * 2 + nt_) * 32) + kc_) * 64 + l_];
  }

  // cell-thread mapping: one (row, d) per thread
  const int lr = tid >> 3, dl = tid & 7;
  const int row_c = rg * 64 + lr, d_c = cg * 8 + dl;
  float c0r = c0init[row_c * 512 + d_c];
  float c1r = c1init[row_c * 512 + d_c];
  float b0A_[4], b0B_[4], b1_[4];
#pragma unroll
  for (int g = 0; g < 4; g++) {
    int col = cg * 32 + dl * 4 + g;
    b0A_[g] = bias0A[col]; b0B_[g] = bias0B[col]; b1_[g] = bias1[col];
  }
  // h write offset in A-frag layout (shorts)
  const int hoff = (((row_c >> 4) * 16 + (cg >> 2)) * 64 + (cg & 3) * 16 + (row_c & 15)) * 8 + (d_c & 7);

  short* h0bufs[2] = { h0b0, h0b1 };
  short* h1bufs[2] = { h1b0, h1b1 };

  __syncthreads();

  for (int t = 0; t < 256; t++) {
    // ================= phase L0 =================
    floatx4 acc = {0.f, 0.f, 0.f, 0.f};
    {  // seg1: x-embed part (no dependency — runs before any wait)
      const short8* Ax = xembF + (long)((t * 16 + rt) * 16) * 64 + lane;
      const short8* Bx = B0Bg + (long)((cg * 2 + nt) * 48) * 64 + lane;
#pragma unroll
      for (int kc = 0; kc < 16; kc++)
        acc = MFMA(Ax[kc * 64], Bx[kc * 64], acc);
    }
    // seg2: h0(t-1)
    if (t > 0) {
      if (tid == 0)
        while (__hip_atomic_load(h0done + (t - 1), __ATOMIC_ACQUIRE, __HIP_MEMORY_SCOPE_AGENT) < NBLK)
          __builtin_amdgcn_s_sleep(1);
      __syncthreads();
    }
    {
      const short8* Ah = (const short8*)h0bufs[(t + 1) & 1] + rt * 1024 + lane;
      const short8* Bh = ldsB0 + nt * 2048 + lane;
#pragma unroll
      for (int kc = 0; kc < 16; kc++)
        acc = MFMA(Ah[kc * 64], Bh[kc * 64], acc);
    }
    // seg3: h1(t-1) via fold (t>0) or pred0 (t==0)
    if (t > 0) {
      if (tid == 0)
        while (__hip_atomic_load(h1done + (t - 1), __ATOMIC_ACQUIRE, __HIP_MEMORY_SCOPE_AGENT) < NBLK)
          __builtin_amdgcn_s_sleep(1);
      __syncthreads();
      const short8* Af = (const short8*)h1bufs[(t + 1) & 1] + rt * 1024 + lane;
      const short8* Bf = ldsB0 + nt * 2048 + 1024 + lane;
#pragma unroll
      for (int kc = 0; kc < 16; kc++)
        acc = MFMA(Af[kc * 64], Bf[kc * 64], acc);
    } else {
      const short8* Ap = (const short8*)pred0;
#pragma unroll
      for (int kc = 0; kc < 2; kc++) {
        short8 a = Ap[(rt * 16 + (lane & 15)) * 8 + kc * 4 + (lane >> 4)];
        short8 b = B0Ag[(long)(((cg * 2 + nt) * 34) + 32 + kc) * 64 + lane];
        acc = MFMA(a, b, acc);
      }
    }
    // epilogue L0: gates -> LDS -> cell
    {
      int lrw = mt * 16 + (lane >> 4) * 4;
      int colw = nt * 16 + (lane & 15);
#pragma unroll
      for (int r = 0; r < 4; r++) gsm[(lrw + r) * 33 + colw] = acc[r];
    }
    __syncthreads();
    {
      float gi = gsm[lr * 33 + dl * 4 + 0] + (t ? b0B_[0] : b0A_[0]);
      float gf = gsm[lr * 33 + dl * 4 + 1] + (t ? b0B_[1] : b0A_[1]);
      float gg = gsm[lr * 33 + dl * 4 + 2] + (t ? b0B_[2] : b0A_[2]);
      float go = gsm[lr * 33 + dl * 4 + 3] + (t ? b0B_[3] : b0A_[3]);
      float is = 1.f / (1.f + __expf(-gi));
      float fs = 1.f / (1.f + __expf(-gf));
      float os = 1.f / (1.f + __expf(-go));
      float gt = tanhf(gg);
      c0r = fs * c0r + is * gt;
      float hn = os * tanhf(c0r);
      h0bufs[t & 1][hoff] = f2bf(hn);
    }
    __threadfence();
    __syncthreads();
    if (tid == 0)
      __hip_atomic_fetch_add(h0done + t, 1, __ATOMIC_RELEASE, __HIP_MEMORY_SCOPE_AGENT);

    // ================= phase L1 =================
    if (tid == 0)
      while (__hip_atomic_load(h0done + t, __ATOMIC_ACQUIRE, __HIP_MEMORY_SCOPE_AGENT) < NBLK)
        __builtin_amdgcn_s_sleep(1);
    __syncthreads();
    floatx4 acc1 = {0.f, 0.f, 0.f, 0.f};
    {
      const short8* Ah = (const short8*)h0bufs[t & 1] + rt * 1024 + lane;
      const short8* Bh = ldsB1 + nt * 2048 + lane;
#pragma unroll
      for (int kc = 0; kc < 16; kc++)
        acc1 = MFMA(Ah[kc * 64], Bh[kc * 64], acc1);
      const short8* Ap = (const short8*)h1bufs[(t + 1) & 1] + rt * 1024 + lane;
      const short8* Bp = ldsB1 + nt * 2048 + 1024 + lane;
#pragma unroll
      for (int kc = 0; kc < 16; kc++)
        acc1 = MFMA(Ap[kc * 64], Bp[kc * 64], acc1);
    }
    {
      int lrw = mt * 16 + (lane >> 4) * 4;
      int colw = nt * 16 + (lane & 15);
#pragma unroll
      for (int r = 0; r < 4; r++) gsm[(lrw + r) * 33 + colw] = acc1[r];
    }
    __syncthreads();
    {
      float gi = gsm[lr * 33 + dl * 4 + 0] + b1_[0];
      float gf = gsm[lr * 33 + dl * 4 + 1] + b1_[1];
      float gg = gsm[lr * 33 + dl * 4 + 2] + b1_[2];
      float go = gsm[lr * 33 + dl * 4 + 3] + b1_[3];
      float is = 1.f / (1.f + __expf(-gi));
      float fs = 1.f / (1.f + __expf(-gf));
      float os = 1.f / (1.f + __expf(-go));
      float gt = tanhf(gg);
      c1r = fs * c1r + is * gt;
      float hn = os * tanhf(c1r);
      h1bufs[t & 1][hoff] = f2bf(hn);
      ctxo[(long)row_c * CTXSTR + t * CTX + d_c] = hn;
    }
    __threadfence();
    __syncthreads();
    if (tid == 0)
      __hip_atomic_fetch_add(h1done + t, 1, __ATOMIC_RELEASE, __HIP_MEMORY_SCOPE_AGENT);
  }
}

extern "C" void kernel_launch(void* const* d_in, const int* in_sizes, int n_in,
                              void* d_out, int out_size, void* d_ws, size_t ws_size,
                              hipStream_t stream)
{
  const float* x       = (const float*)d_in[0];
  const float* init_p  = (const float*)d_in[1];
  const float* embed_W = (const float*)d_in[2];
  const float* embed_b = (const float*)d_in[3];
  const float* ni_W1   = (const float*)d_in[4];
  const float* ni_b1   = (const float*)d_in[5];
  const float* ni_W2   = (const float*)d_in[6];
  const float* ni_b2   = (const float*)d_in[7];
  const float* ni_W3   = (const float*)d_in[8];
  const float* ni_b3   = (const float*)d_in[9];
  const float* Wih0    = (const float*)d_in[10];
  const float* Whh0    = (const float*)d_in[11];
  const float* bih0    = (const float*)d_in[12];
  const float* bhh0    = (const float*)d_in[13];
  const float* Wih1    = (const float*)d_in[14];
  const float* Whh1    = (const float*)d_in[15];
  const float* bih1    = (const float*)d_in[16];
  const float* bhh1    = (const float*)d_in[17];
  const float* dec_W   = (const float*)d_in[18];
  const float* dec_b   = (const float*)d_in[19];
  float* out = (float*)d_out;
  char* ws = (char*)d_ws;
  (void)in_sizes; (void)n_in; (void)out_size; (void)ws_size;

  // workspace layout (bytes, 256-aligned)
  short* xembF = (short*)(ws + 0);            // 67108864
  short* B0A   = (short*)(ws + 67108864);     // 34*32*2048*2 = 4456448
  short* B0B   = (short*)(ws + 71565312);     // 48*32*2048*2 = 6291456
  short* B1p   = (short*)(ws + 77856768);     // 32*32*2048*2 = 4194304
  short* h0b0  = (short*)(ws + 82051072);     // 262144 each
  short* h0b1  = (short*)(ws + 82313216);
  short* h1b0  = (short*)(ws + 82575360);
  short* h1b1  = (short*)(ws + 82837504);
  float* c0    = (float*)(ws + 83099648);     // 524288 each
  float* c1    = (float*)(ws + 83623936);
  float* bias0A = (float*)(ws + 84148224);
  float* bias0B = (float*)(ws + 84156416);
  float* bias1  = (float*)(ws + 84164608);
  short* pred0pad = (short*)(ws + 84172800);  // 32768
  float* z1    = (float*)(ws + 84205568);     // 524288
  float* z2    = (float*)(ws + 84729856);     // 1048576
  int*   flags = (int*)(ws + 85778432);       // 512 ints
  int* h0done = flags;
  int* h1done = flags + 256;

  // ---- prep ----
  pack_b<<<8704, 256, 0, stream>>>(B0A, 34, 0, Wih0, Whh0, Wih1, Whh1, dec_W);
  pack_b<<<12288, 256, 0, stream>>>(B0B, 48, 1, Wih0, Whh0, Wih1, Whh1, dec_W);
  pack_b<<<8192, 256, 0, stream>>>(B1p, 32, 2, Wih0, Whh0, Wih1, Whh1, dec_W);
  prep_small<<<64, 256, 0, stream>>>(bias0A, bias0B, bias1, pred0pad, flags,
                                     bih0, bhh0, bih1, bhh1, Wih0, dec_b, init_p);
  // x_emb -> bf16 A-frag layout
  gemm_f32<<<dim3(8, 1024), 256, 0, stream>>>(x, 34, embed_W, embed_b,
      65536, 512, 34, 1, nullptr, nullptr, xembF, nullptr, nullptr, nullptr);
  // init MLP -> h (frag, bufs[1]) / c (row-major)
  gemm_f32<<<dim3(8, 4), 256, 0, stream>>>(init_p, 85, ni_W1, ni_b1,
      256, 512, 85, 0, z1, nullptr, nullptr, nullptr, nullptr, nullptr);
  gemm_f32<<<dim3(16, 4), 256, 0, stream>>>(z1, 512, ni_W2, ni_b2,
      256, 1024, 512, 0, z2, nullptr, nullptr, nullptr, nullptr, nullptr);
  gemm_f32<<<dim3(32, 4), 256, 0, stream>>>(z2, 1024, ni_W3, ni_b3,
      256, 2048, 1024, 2, nullptr, nullptr, h0b1, h1b1, c0, c1);

  // ---- persistent scan (single cooperative launch) ----
  hipFuncSetAttribute((const void*)scan_persist,
                      hipFuncAttributeMaxDynamicSharedMemorySize, LDSZ);
  const short8* xembF8 = (const short8*)xembF;
  const short8* B0A8 = (const short8*)B0A;
  const short8* B0B8 = (const short8*)B0B;
  const short8* B18  = (const short8*)B1p;
  const short* pred0c = pred0pad;
  float* ctxo = out + CTXOFF;
  void* args[] = {
    (void*)&xembF8, (void*)&B0A8, (void*)&B0B8, (void*)&B18,
    (void*)&h0b0, (void*)&h0b1, (void*)&h1b0, (void*)&h1b1,
    (void*)&c0, (void*)&c1,
    (void*)&bias0A, (void*)&bias0B, (void*)&bias1, (void*)&pred0c,
    (void*)&ctxo, (void*)&h0done, (void*)&h1done
  };
  hipLaunchCooperativeKernel((const void*)scan_persist, dim3(NBLK), dim3(NTHR),
                             args, LDSZ, stream);

  // ---- preds = ctx @ dec_W + dec_b -> pred_kp3d + motion_context[...,512:] ----
  gemm_f32<<<dim3(1, 1024), 256, 0, stream>>>(out + CTXOFF, CTX, dec_W, dec_b,
      65536, NJ3, 512, 3, out, out + CTXOFF, nullptr, nullptr, nullptr, nullptr);
}

// Round 3
// 9649.459 us; speedup vs baseline: 3.0092x; 3.0092x over previous
//
#include <hip/hip_runtime.h>

#define B_N 256
#define F_N 256
#define NJ3 51
#define DH 512
#define G4 2048
#define CTX 563
#define CTXSTR (F_N * CTX)            // 144128
#define OUT0 (B_N * F_N * NJ3)        // 3342336
#define CTXOFF OUT0
#define NBLK 256
#define NTHR 512
#define LDSZ (65536 + 65536 + 2 * 64 * 33 * 4)   // B0 + B1 + gsm[2][64][33] = 147968

typedef __attribute__((ext_vector_type(8))) short short8;
typedef __attribute__((ext_vector_type(4))) float floatx4;

__device__ __forceinline__ short f2bf(float f) {
  unsigned u = __float_as_uint(f);
  u = (u + 0x7fffu + ((u >> 16) & 1u)) >> 16;
  return (short)u;
}

#define MFMA(a, b, c) __builtin_amdgcn_mfma_f32_16x16x32_bf16((a), (b), (c), 0, 0, 0)

// ---------------------------------------------------------------------------
// Generic fp32 tiled GEMM (pre/post passes). Modes as before.
// ---------------------------------------------------------------------------
__global__ __launch_bounds__(256) void gemm_f32(
    const float* __restrict__ A, int lda,
    const float* __restrict__ Bw, const float* __restrict__ bias,
    int M, int N, int K, int mode,
    float* __restrict__ out_f, float* __restrict__ out_f2,
    short* __restrict__ out_h0, short* __restrict__ out_h1,
    float* __restrict__ out_c0, float* __restrict__ out_c1)
{
  __shared__ float As[16][64];
  __shared__ float Bs[16][68];
  int tid = threadIdx.x;
  int n0 = blockIdx.x * 64, m0 = blockIdx.y * 64;
  float acc[4][4] = {{0.f}};
  int ar = tid >> 2, ak = (tid & 3) * 4;
  int bk = tid >> 6, bn = tid & 63;
  int tm = (tid >> 4) * 4, tn = (tid & 15) * 4;
  for (int k0 = 0; k0 < K; k0 += 16) {
#pragma unroll
    for (int i = 0; i < 4; i++) {
      int kk = ak + i;
      float v = 0.f;
      if (k0 + kk < K) v = A[(long)(m0 + ar) * lda + k0 + kk];
      As[kk][ar] = v;
    }
#pragma unroll
    for (int i = 0; i < 4; i++) {
      int kk = bk + i * 4;
      float v = 0.f;
      if (k0 + kk < K && n0 + bn < N) v = Bw[(long)(k0 + kk) * N + n0 + bn];
      Bs[kk][bn] = v;
    }
    __syncthreads();
#pragma unroll
    for (int kk = 0; kk < 16; kk++) {
      float a0[4], b0[4];
#pragma unroll
      for (int i = 0; i < 4; i++) a0[i] = As[kk][tm + i];
#pragma unroll
      for (int j = 0; j < 4; j++) b0[j] = Bs[kk][tn + j];
#pragma unroll
      for (int i = 0; i < 4; i++)
#pragma unroll
        for (int j = 0; j < 4; j++) acc[i][j] += a0[i] * b0[j];
    }
    __syncthreads();
  }
#pragma unroll
  for (int i = 0; i < 4; i++) {
    int m = m0 + tm + i;
#pragma unroll
    for (int j = 0; j < 4; j++) {
      int n = n0 + tn + j;
      if (n >= N) continue;
      float v = acc[i][j] + bias[n];
      if (mode == 0) {
        out_f[(long)m * N + n] = fmaxf(v, 0.f);
      } else if (mode == 1) {
        int b = m >> 8, f = m & 255;
        long idx = ((((long)f * 16 + (b >> 4)) * 16 + (n >> 5)) * 64 +
                    ((n >> 3) & 3) * 16 + (b & 15)) * 8 + (n & 7);
        out_h0[idx] = f2bf(v);
      } else if (mode == 2) {
        int d = n & 511;
        long fi = (((long)(m >> 4) * 16 + (d >> 5)) * 64 +
                   ((d >> 3) & 3) * 16 + (m & 15)) * 8 + (d & 7);
        if (n < 512)       out_h0[fi] = f2bf(v);
        else if (n < 1024) out_h1[fi] = f2bf(v);
        else if (n < 1536) out_c0[m * 512 + d] = v;
        else               out_c1[m * 512 + d] = v;
      } else {
        out_f[(long)m * NJ3 + n] = v;
        out_f2[(long)m * CTX + 512 + n] = v;
      }
    }
  }
}

// ---------------------------------------------------------------------------
// Pack weights (fp32 -> bf16) into MFMA B-fragment layout.
// dst[((ntg*KC + kc)*64 + lane)*8 + j] = B[kc*32+(lane>>4)*8+j][ntg*16+(lane&15)]
// col j' = 4*d + gate  ->  original gate row jo = gate*512 + d
// mode 0: B0A (t=0): [Wih0_x(512) | Whh0(512) | Wih0_pred pad64]  KC=34
// mode 1: B0B (t>0): [Wih0_x(512) | Whh0(512) | dec_W@Wp^T(512)]  KC=48
// mode 2: B1:        [Wih1(512)   | Whh1(512)]                     KC=32
// ---------------------------------------------------------------------------
__global__ __launch_bounds__(256) void pack_b(
    short* __restrict__ dst, int KC, int mode,
    const float* __restrict__ Wih0, const float* __restrict__ Whh0,
    const float* __restrict__ Wih1, const float* __restrict__ Whh1,
    const float* __restrict__ dec_W)
{
  int idx = blockIdx.x * 256 + threadIdx.x;
  int total = KC * 32 * G4;
  if (idx >= total) return;
  int j = idx & 7;
  int l = (idx >> 3) & 63;
  int tt = idx >> 9;
  int kc = tt % KC;
  int nt = tt / KC;
  int k = kc * 32 + ((l >> 4) << 3) + j;
  int jp = nt * 16 + (l & 15);
  int jo = ((jp & 3) << 9) + (jp >> 2);
  float v = 0.f;
  if (mode == 0) {
    if (k < 512) v = Wih0[jo * 563 + k];
    else if (k < 1024) v = Whh0[jo * 512 + k - 512];
    else { int p = k - 1024; v = (p < NJ3) ? Wih0[jo * 563 + 512 + p] : 0.f; }
  } else if (mode == 1) {
    if (k < 512) v = Wih0[jo * 563 + k];
    else if (k < 1024) v = Whh0[jo * 512 + k - 512];
    else {
      int dd = k - 1024;
      float s = 0.f;
      for (int p = 0; p < NJ3; p++) s += dec_W[dd * NJ3 + p] * Wih0[jo * 563 + 512 + p];
      v = s;
    }
  } else {
    if (k < 512) v = Wih1[jo * 512 + k];
    else v = Whh1[jo * 512 + k - 512];
  }
  dst[idx] = f2bf(v);
}

// biases in j'=4d+g order; bias0B includes dec_b fold; pred0pad bf16 [256][64];
// zero the 4096 flag counters.
__global__ __launch_bounds__(256) void prep_small(
    float* __restrict__ bias0A, float* __restrict__ bias0B, float* __restrict__ bias1,
    short* __restrict__ pred0pad, int* __restrict__ flags,
    const float* __restrict__ bih0, const float* __restrict__ bhh0,
    const float* __restrict__ bih1, const float* __restrict__ bhh1,
    const float* __restrict__ Wih0, const float* __restrict__ dec_b,
    const float* __restrict__ init_p)
{
  int i = blockIdx.x * 256 + threadIdx.x;
  if (i < G4) {
    int jo = ((i & 3) << 9) + (i >> 2);
    float b0 = bih0[jo] + bhh0[jo];
    bias0A[i] = b0;
    float s = 0.f;
    for (int p = 0; p < NJ3; p++) s += dec_b[p] * Wih0[jo * 563 + 512 + p];
    bias0B[i] = b0 + s;
    bias1[i] = bih1[jo] + bhh1[jo];
  }
  if (i < 16384) {
    int b = i >> 6, p = i & 63;
    pred0pad[i] = (p < NJ3) ? f2bf(init_p[b * 85 + p]) : (short)0;
  }
  if (i < 4096) flags[i] = 0;
}

// ---------------------------------------------------------------------------
// Persistent cooperative scan. 256 blocks x 512 threads, 1 block/CU.
// Block tile: 64 rows (rg = bid>>6) x 32 gate-cols (cg = bid&63).
// Waves: (nt = k-half, mt = rowtile). K split across nt eliminates duplicate
// A reads; partial gate sums combined through gsm[2][64][33].
// Sync: per-rg flag counters (64 blocks/group). Producers: sc1 relaxed atomic
// stores + syncthreads(vmcnt drain) + relaxed add. Consumers: relaxed poll ->
// one acquire-agent fence (single buffer_inv) -> plain cached 16B loads.
// h1(t-1) frags (fold) reused for L1; h0(t) frags (L1) reused for next L0:
// only 2 waits and 2 cross-block read segments per step. c-state in registers.
// ---------------------------------------------------------------------------
__global__ __launch_bounds__(512, 2) void scan_persist(
    const short8* __restrict__ xembF, const short8* __restrict__ B0Ag,
    const short8* __restrict__ B0Bg, const short8* __restrict__ B1g,
    short* __restrict__ h0b0, short* __restrict__ h0b1,
    short* __restrict__ h1b0, short* __restrict__ h1b1,
    const float* __restrict__ c0init, const float* __restrict__ c1init,
    const float* __restrict__ bias0A, const float* __restrict__ bias0B,
    const float* __restrict__ bias1, const short* __restrict__ pred0,
    float* __restrict__ ctxo, int* __restrict__ flags)
{
  extern __shared__ char smem[];
  short8* ldsB0 = (short8*)smem;              // [ct2][kr32][lane64]: hh|fold
  short8* ldsB1 = (short8*)(smem + 65536);    // [ct2][kr32][lane64]: h0|h1
  float*  gsm   = (float*)(smem + 131072);    // [nt2][64][33]

  const int tid = threadIdx.x;
  const int lane = tid & 63, wave = tid >> 6;
  const int cg = blockIdx.x & 63, rg = blockIdx.x >> 6;
  const int nt = wave >> 2, mt = wave & 3;
  const int rt = rg * 4 + mt;                 // global A rowtile (0..15)
  const int kh = nt * 8;                      // kc-half base

  // stage weight slices into LDS (one-time)
  for (int i = tid; i < 4096; i += NTHR) {
    int ct_ = i >> 11, kr_ = (i >> 6) & 31, l_ = i & 63;
    ldsB0[i] = B0Bg[(((cg * 2 + ct_) * 48) + 16 + kr_) * 64 + l_];
    ldsB1[i] = B1g[(((cg * 2 + ct_) * 32) + kr_) * 64 + l_];
  }

  // cell-thread mapping: one (row, d) per thread
  const int lr = tid >> 3, dl = tid & 7;
  const int row_c = rg * 64 + lr, d_c = cg * 8 + dl;
  float c0r = c0init[row_c * 512 + d_c];
  float c1r = c1init[row_c * 512 + d_c];
  float b0A_[4], b0B_[4], b1_[4];
#pragma unroll
  for (int g = 0; g < 4; g++) {
    int col = cg * 32 + dl * 4 + g;
    b0A_[g] = bias0A[col]; b0B_[g] = bias0B[col]; b1_[g] = bias1[col];
  }
  // h write offset (shorts) in A-frag layout; int index for paired store
  const int hoff = (((row_c >> 4) * 16 + (cg >> 2)) * 64 + (cg & 3) * 16 + (row_c & 15)) * 8 + dl;
  const int hoffw = hoff >> 1;

  int* fl_h0 = flags + rg * 1024;
  int* fl_h1 = flags + rg * 1024 + 512;
  short* h0bufs[2] = { h0b0, h0b1 };
  short* h1bufs[2] = { h1b0, h1b1 };

  // preload register caches with h(-1)
  short8 hc0[8], hc1[8];
  {
    const short8* H0 = (const short8*)h0b1;
    const short8* H1 = (const short8*)h1b1;
#pragma unroll
    for (int q = 0; q < 8; q++) {
      hc0[q] = H0[(rt * 16 + kh + q) * 64 + lane];
      hc1[q] = H1[(rt * 16 + kh + q) * 64 + lane];
    }
  }
  __syncthreads();

  for (int t = 0; t < 256; t++) {
    // ================= phase L0 =================
    floatx4 accA = {0.f, 0.f, 0.f, 0.f}, accB = {0.f, 0.f, 0.f, 0.f};
    {  // seg_x: x-embed part (no dependency)
      const short8* Ax  = xembF + (long)((t * 16 + rt) * 16 + kh) * 64 + lane;
      const short8* BxA = B0Bg + (long)((cg * 2 + 0) * 48 + kh) * 64 + lane;
      const short8* BxB = B0Bg + (long)((cg * 2 + 1) * 48 + kh) * 64 + lane;
      short8 a[8];
#pragma unroll
      for (int q = 0; q < 8; q++) a[q] = Ax[q * 64];
#pragma unroll
      for (int q = 0; q < 8; q++) {
        accA = MFMA(a[q], BxA[q * 64], accA);
        accB = MFMA(a[q], BxB[q * 64], accB);
      }
    }
    // seg_h0: h0(t-1) from register cache (no wait, no load)
#pragma unroll
    for (int q = 0; q < 8; q++) {
      accA = MFMA(hc0[q], ldsB0[(kh + q) * 64 + lane], accA);
      accB = MFMA(hc0[q], ldsB0[(32 + kh + q) * 64 + lane], accB);
    }
    // seg_fold: h1(t-1) (t>0) or pred0 (t==0)
    if (t > 0) {
      if (tid == 0)
        while (__hip_atomic_load(&fl_h1[t - 1], __ATOMIC_RELAXED, __HIP_MEMORY_SCOPE_AGENT) < 64)
          __builtin_amdgcn_s_sleep(1);
      __syncthreads();
      __builtin_amdgcn_fence(__ATOMIC_ACQUIRE, "agent");
      const short8* Hp = (const short8*)h1bufs[(t + 1) & 1];
#pragma unroll
      for (int q = 0; q < 8; q++) hc1[q] = Hp[(rt * 16 + kh + q) * 64 + lane];
#pragma unroll
      for (int q = 0; q < 8; q++) {
        accA = MFMA(hc1[q], ldsB0[(16 + kh + q) * 64 + lane], accA);
        accB = MFMA(hc1[q], ldsB0[(48 + kh + q) * 64 + lane], accB);
      }
    } else {
      short8 a = ((const short8*)pred0)[(rt * 16 + (lane & 15)) * 8 + nt * 4 + (lane >> 4)];
      accA = MFMA(a, B0Ag[(long)((cg * 2 + 0) * 34 + 32 + nt) * 64 + lane], accA);
      accB = MFMA(a, B0Ag[(long)((cg * 2 + 1) * 34 + 32 + nt) * 64 + lane], accB);
    }
    // epilogue L0: partial gates -> gsm halves
    {
      int grow = nt * 64 + mt * 16 + (lane >> 4) * 4;
      int gc = lane & 15;
#pragma unroll
      for (int r = 0; r < 4; r++) {
        gsm[(grow + r) * 33 + gc] = accA[r];
        gsm[(grow + r) * 33 + 16 + gc] = accB[r];
      }
    }
    __syncthreads();
    {
      const float* bb = t ? b0B_ : b0A_;
      int g0 = lr * 33 + dl * 4, g1 = 2112 + g0;
      float gi = gsm[g0 + 0] + gsm[g1 + 0] + bb[0];
      float gf = gsm[g0 + 1] + gsm[g1 + 1] + bb[1];
      float gg = gsm[g0 + 2] + gsm[g1 + 2] + bb[2];
      float go = gsm[g0 + 3] + gsm[g1 + 3] + bb[3];
      float is = 1.f / (1.f + __expf(-gi));
      float fs = 1.f / (1.f + __expf(-gf));
      float os = 1.f / (1.f + __expf(-go));
      float gt = tanhf(gg);
      c0r = fs * c0r + is * gt;
      float hn = os * tanhf(c0r);
      unsigned hv = (unsigned)(unsigned short)f2bf(hn);
      unsigned ov = (unsigned)__shfl_xor((int)hv, 1);
      if (!(tid & 1))
        __hip_atomic_store((int*)h0bufs[t & 1] + hoffw, (int)(hv | (ov << 16)),
                           __ATOMIC_RELAXED, __HIP_MEMORY_SCOPE_AGENT);
    }
    __syncthreads();   // drains vmcnt: sc1 stores at coherence point
    if (tid == 0)
      __hip_atomic_fetch_add(&fl_h0[t], 1, __ATOMIC_RELAXED, __HIP_MEMORY_SCOPE_AGENT);

    // ================= phase L1 =================
    floatx4 acc1A = {0.f, 0.f, 0.f, 0.f}, acc1B = {0.f, 0.f, 0.f, 0.f};
    // seg2: h1(t-1) from register cache (before the wait)
#pragma unroll
    for (int q = 0; q < 8; q++) {
      acc1A = MFMA(hc1[q], ldsB1[(16 + kh + q) * 64 + lane], acc1A);
      acc1B = MFMA(hc1[q], ldsB1[(48 + kh + q) * 64 + lane], acc1B);
    }
    if (tid == 0)
      while (__hip_atomic_load(&fl_h0[t], __ATOMIC_RELAXED, __HIP_MEMORY_SCOPE_AGENT) < 64)
        __builtin_amdgcn_s_sleep(1);
    __syncthreads();
    __builtin_amdgcn_fence(__ATOMIC_ACQUIRE, "agent");
    {  // seg1: h0(t); cache frags for next step's L0
      const short8* Hc = (const short8*)h0bufs[t & 1];
#pragma unroll
      for (int q = 0; q < 8; q++) hc0[q] = Hc[(rt * 16 + kh + q) * 64 + lane];
#pragma unroll
      for (int q = 0; q < 8; q++) {
        acc1A = MFMA(hc0[q], ldsB1[(kh + q) * 64 + lane], acc1A);
        acc1B = MFMA(hc0[q], ldsB1[(32 + kh + q) * 64 + lane], acc1B);
      }
    }
    {
      int grow = nt * 64 + mt * 16 + (lane >> 4) * 4;
      int gc = lane & 15;
#pragma unroll
      for (int r = 0; r < 4; r++) {
        gsm[(grow + r) * 33 + gc] = acc1A[r];
        gsm[(grow + r) * 33 + 16 + gc] = acc1B[r];
      }
    }
    __syncthreads();
    {
      int g0 = lr * 33 + dl * 4, g1 = 2112 + g0;
      float gi = gsm[g0 + 0] + gsm[g1 + 0] + b1_[0];
      float gf = gsm[g0 + 1] + gsm[g1 + 1] + b1_[1];
      float gg = gsm[g0 + 2] + gsm[g1 + 2] + b1_[2];
      float go = gsm[g0 + 3] + gsm[g1 + 3] + b1_[3];
      float is = 1.f / (1.f + __expf(-gi));
      float fs = 1.f / (1.f + __expf(-gf));
      float os = 1.f / (1.f + __expf(-go));
      float gt = tanhf(gg);
      c1r = fs * c1r + is * gt;
      float hn = os * tanhf(c1r);
      unsigned hv = (unsigned)(unsigned short)f2bf(hn);
      unsigned ov = (unsigned)__shfl_xor((int)hv, 1);
      if (!(tid & 1))
        __hip_atomic_store((int*)h1bufs[t & 1] + hoffw, (int)(hv | (ov << 16)),
                           __ATOMIC_RELAXED, __HIP_MEMORY_SCOPE_AGENT);
      ctxo[(long)row_c * CTXSTR + t * CTX + d_c] = hn;
    }
    __syncthreads();
    if (tid == 0)
      __hip_atomic_fetch_add(&fl_h1[t], 1, __ATOMIC_RELAXED, __HIP_MEMORY_SCOPE_AGENT);
  }
}

extern "C" void kernel_launch(void* const* d_in, const int* in_sizes, int n_in,
                              void* d_out, int out_size, void* d_ws, size_t ws_size,
                              hipStream_t stream)
{
  const float* x       = (const float*)d_in[0];
  const float* init_p  = (const float*)d_in[1];
  const float* embed_W = (const float*)d_in[2];
  const float* embed_b = (const float*)d_in[3];
  const float* ni_W1   = (const float*)d_in[4];
  const float* ni_b1   = (const float*)d_in[5];
  const float* ni_W2   = (const float*)d_in[6];
  const float* ni_b2   = (const float*)d_in[7];
  const float* ni_W3   = (const float*)d_in[8];
  const float* ni_b3   = (const float*)d_in[9];
  const float* Wih0    = (const float*)d_in[10];
  const float* Whh0    = (const float*)d_in[11];
  const float* bih0    = (const float*)d_in[12];
  const float* bhh0    = (const float*)d_in[13];
  const float* Wih1    = (const float*)d_in[14];
  const float* Whh1    = (const float*)d_in[15];
  const float* bih1    = (const float*)d_in[16];
  const float* bhh1    = (const float*)d_in[17];
  const float* dec_W   = (const float*)d_in[18];
  const float* dec_b   = (const float*)d_in[19];
  float* out = (float*)d_out;
  char* ws = (char*)d_ws;
  (void)in_sizes; (void)n_in; (void)out_size; (void)ws_size;

  // workspace layout (bytes, 256-aligned)
  short* xembF = (short*)(ws + 0);            // 67108864
  short* B0A   = (short*)(ws + 67108864);     // 4456448
  short* B0B   = (short*)(ws + 71565312);     // 6291456
  short* B1p   = (short*)(ws + 77856768);     // 4194304
  short* h0b0  = (short*)(ws + 82051072);     // 262144 each
  short* h0b1  = (short*)(ws + 82313216);
  short* h1b0  = (short*)(ws + 82575360);
  short* h1b1  = (short*)(ws + 82837504);
  float* c0    = (float*)(ws + 83099648);     // 524288 each
  float* c1    = (float*)(ws + 83623936);
  float* bias0A = (float*)(ws + 84148224);
  float* bias0B = (float*)(ws + 84156416);
  float* bias1  = (float*)(ws + 84164608);
  short* pred0pad = (short*)(ws + 84172800);  // 32768
  float* z1    = (float*)(ws + 84205568);     // 524288
  float* z2    = (float*)(ws + 84729856);     // 1048576
  int*   flags = (int*)(ws + 85778432);       // 4096 ints (4 rg x 1024)

  // ---- prep ----
  pack_b<<<8704, 256, 0, stream>>>(B0A, 34, 0, Wih0, Whh0, Wih1, Whh1, dec_W);
  pack_b<<<12288, 256, 0, stream>>>(B0B, 48, 1, Wih0, Whh0, Wih1, Whh1, dec_W);
  pack_b<<<8192, 256, 0, stream>>>(B1p, 32, 2, Wih0, Whh0, Wih1, Whh1, dec_W);
  prep_small<<<64, 256, 0, stream>>>(bias0A, bias0B, bias1, pred0pad, flags,
                                     bih0, bhh0, bih1, bhh1, Wih0, dec_b, init_p);
  // x_emb -> bf16 A-frag layout
  gemm_f32<<<dim3(8, 1024), 256, 0, stream>>>(x, 34, embed_W, embed_b,
      65536, 512, 34, 1, nullptr, nullptr, xembF, nullptr, nullptr, nullptr);
  // init MLP -> h (frag, bufs[1]) / c (row-major)
  gemm_f32<<<dim3(8, 4), 256, 0, stream>>>(init_p, 85, ni_W1, ni_b1,
      256, 512, 85, 0, z1, nullptr, nullptr, nullptr, nullptr, nullptr);
  gemm_f32<<<dim3(16, 4), 256, 0, stream>>>(z1, 512, ni_W2, ni_b2,
      256, 1024, 512, 0, z2, nullptr, nullptr, nullptr, nullptr, nullptr);
  gemm_f32<<<dim3(32, 4), 256, 0, stream>>>(z2, 1024, ni_W3, ni_b3,
      256, 2048, 1024, 2, nullptr, nullptr, h0b1, h1b1, c0, c1);

  // ---- persistent scan (single cooperative launch) ----
  hipFuncSetAttribute((const void*)scan_persist,
                      hipFuncAttributeMaxDynamicSharedMemorySize, LDSZ);
  const short8* xembF8 = (const short8*)xembF;
  const short8* B0A8 = (const short8*)B0A;
  const short8* B0B8 = (const short8*)B0B;
  const short8* B18  = (const short8*)B1p;
  const short* pred0c = pred0pad;
  float* ctxo = out + CTXOFF;
  void* args[] = {
    (void*)&xembF8, (void*)&B0A8, (void*)&B0B8, (void*)&B18,
    (void*)&h0b0, (void*)&h0b1, (void*)&h1b0, (void*)&h1b1,
    (void*)&c0, (void*)&c1,
    (void*)&bias0A, (void*)&bias0B, (void*)&bias1, (void*)&pred0c,
    (void*)&ctxo, (void*)&flags
  };
  hipLaunchCooperativeKernel((const void*)scan_persist, dim3(NBLK), dim3(NTHR),
                             args, LDSZ, stream);

  // ---- preds = ctx @ dec_W + dec_b -> pred_kp3d + motion_context[...,512:] ----
  gemm_f32<<<dim3(1, 1024), 256, 0, stream>>>(out + CTXOFF, CTX, dec_W, dec_b,
      65536, NJ3, 512, 3, out, out + CTXOFF, nullptr, nullptr, nullptr, nullptr);
}